// Round 11
// baseline (4536.153 us; speedup 1.0000x reference)
//
#include <hip/hip_runtime.h>
#include <stdint.h>

// ============================================================================
// World: d_out = f32[33,554,432]: [0..16.7M) out f32; [16.7M..33.5M) Re(s) f32.
// ws: pre bf16 (69MB) | u f32 (2MB) | s interleaved bf16 (67MB) = 138.4MB.
// ============================================================================

// ---- GEMM1 (naive, 4 rows/block): pre = x @ pre_w + pre_b -> bf16 ----
__global__ __launch_bounds__(256) void gemm1_naive(const float* __restrict__ A,
                                                   const float* __restrict__ W,
                                                   const float* __restrict__ bias,
                                                   __bf16* __restrict__ out) {
  __shared__ float arow[4][1024];
  const long i0 = (long)blockIdx.y * 4;
#pragma unroll
  for (int r = 0; r < 4; ++r)
    for (int k = threadIdx.x; k < 1024; k += 256)
      arow[r][k] = A[(i0 + r) * 1024 + k];
  __syncthreads();
  const int j = blockIdx.x * 256 + threadIdx.x;
  if (j >= 2112) return;
  float acc0 = bias[j], acc1 = acc0, acc2 = acc0, acc3 = acc0;
  for (int k = 0; k < 1024; ++k) {
    float w = W[(long)k * 2112 + j];
    acc0 = fmaf(arow[0][k], w, acc0);
    acc1 = fmaf(arow[1][k], w, acc1);
    acc2 = fmaf(arow[2][k], w, acc2);
    acc3 = fmaf(arow[3][k], w, acc3);
  }
  out[(i0 + 0) * 2112 + j] = (__bf16)acc0;
  out[(i0 + 1) * 2112 + j] = (__bf16)acc1;
  out[(i0 + 2) * 2112 + j] = (__bf16)acc2;
  out[(i0 + 3) * 2112 + j] = (__bf16)acc3;
}

// ---- u = y * sigmoid(in_gate), layout u[b][m][t] ----
__global__ __launch_bounds__(256) void u_kernel(const __bf16* __restrict__ pre,
                                                float* __restrict__ u) {
  int i = blockIdx.x * 8 + (threadIdx.x >> 5);
  int m = threadIdx.x & 31;
  const __bf16* pr = pre + (long)i * 2112;
  float y = (float)pr[m];
  float g = (float)pr[1056 + m];
  float sg = 1.f / (1.f + expf(-g));
  int b = i >> 11, t = i & 2047;
  u[(long)((b * 32) + m) * 2048 + t] = y * sg;
}

// ---- scan: s_t = gamma*s_{t-1} + u_t ----
// writes: interleaved bf16 (re,im) pairs to ws (GEMM2's A operand)
//         + REAL PART f32 to d_out s-window.
__global__ __launch_bounds__(64) void scan_kernel(const float* __restrict__ u,
                                                  const float* __restrict__ a,
                                                  const float* __restrict__ bfr,
                                                  __bf16* __restrict__ s_bf,
                                                  float* __restrict__ s_re) {
  int blk = blockIdx.x;
  int b = blk >> 4, mp = blk & 15;
  int lane = threadIdx.x;
  int mh = lane >> 5, c = lane & 31;
  int m = mp * 2 + mh;
  const float* ub = u + (long)(b * 32 + m) * 2048;
  float decay = expf(-fabsf(a[m]));
  float gr = decay * cosf(bfr[c]);
  float gi = decay * sinf(bfr[c]);
  float sr = 0.f, si = 0.f;
  long base = (long)b * 2048 * 1024 + m * 32 + c;  // complex-element index
  for (int t = 0; t < 2048; ++t) {
    float uv = ub[t];
    float nr = fmaf(gr, sr, fmaf(-gi, si, uv));
    float ni_ = fmaf(gr, si, gi * sr);
    sr = nr; si = ni_;
    long ci = base + (long)t * 1024;
    s_bf[2 * ci] = (__bf16)sr;
    s_bf[2 * ci + 1] = (__bf16)si;
    s_re[ci] = sr;
  }
}

// ---- GEMM2 (naive, 4 rows/block): z = s_bf @ mix_w + mix_b -> f32 out0 ----
__global__ __launch_bounds__(256) void gemm2_naive(const __bf16* __restrict__ A,
                                                   const float* __restrict__ W,
                                                   const float* __restrict__ bias,
                                                   float* __restrict__ out) {
  __shared__ float arow[4][2048];
  const long i0 = (long)blockIdx.y * 4;
#pragma unroll
  for (int r = 0; r < 4; ++r)
    for (int k = threadIdx.x; k < 2048; k += 256)
      arow[r][k] = (float)A[(i0 + r) * 2048 + k];
  __syncthreads();
  const int j = blockIdx.x * 256 + threadIdx.x;  // 0..1023
  float acc0 = bias[j], acc1 = acc0, acc2 = acc0, acc3 = acc0;
  for (int k = 0; k < 2048; ++k) {
    float w = W[(long)k * 1024 + j];
    acc0 = fmaf(arow[0][k], w, acc0);
    acc1 = fmaf(arow[1][k], w, acc1);
    acc2 = fmaf(arow[2][k], w, acc2);
    acc3 = fmaf(arow[3][k], w, acc3);
  }
  out[(i0 + 0) * 1024 + j] = acc0;
  out[(i0 + 1) * 1024 + j] = acc1;
  out[(i0 + 2) * 1024 + j] = acc2;
  out[(i0 + 3) * 1024 + j] = acc3;
}

// ---- layernorm + gated mix, in place on f32 z rows (1 wave per row) ----
__global__ __launch_bounds__(64) void ln_plain(float* __restrict__ z,
                                               const __bf16* __restrict__ pre) {
  const long row = blockIdx.x;
  float* zp = z + row * 1024;
  const int tid = threadIdx.x;  // 0..63
  float v[16];
  float s = 0.f, ss = 0.f;
#pragma unroll
  for (int q = 0; q < 16; ++q) {
    float x = zp[tid + q * 64];
    v[q] = x; s += x; ss += x * x;
  }
#pragma unroll
  for (int o = 32; o > 0; o >>= 1) {
    s += __shfl_down(s, o, 64);
    ss += __shfl_down(ss, o, 64);
  }
  s = __shfl(s, 0, 64);
  ss = __shfl(ss, 0, 64);
  float mean = s * (1.f / 1024.f);
  float var = ss * (1.f / 1024.f) - mean * mean;
  float rstd = rsqrtf(var + 1e-5f);
  const __bf16* pr = pre + row * 2112;
#pragma unroll
  for (int q = 0; q < 16; ++q) {
    int e = tid + q * 64;
    float th = (float)pr[32 + e];
    float og = (float)pr[1088 + e];
    float g = 1.f / (1.f + expf(-og));
    zp[e] = (v[q] - mean) * rstd * g + th * (1.f - g);
  }
}

extern "C" void kernel_launch(void* const* d_in, const int* in_sizes, int n_in,
                              void* d_out, int out_size, void* d_ws, size_t ws_size,
                              hipStream_t stream) {
  const float* x = (const float*)d_in[0];
  const float* pre_w = (const float*)d_in[1];
  const float* pre_b = (const float*)d_in[2];
  const float* mix_w = (const float*)d_in[3];
  const float* mix_b = (const float*)d_in[4];
  const float* a = (const float*)d_in[5];
  const float* bfr = (const float*)d_in[6];

  char* ws = (char*)d_ws;
  __bf16* pre  = (__bf16*)(ws + 0);          // 69,206,016 B
  float*  u    = (float*)(ws + 69206016);    //  2,097,152 B
  __bf16* s_bf = (__bf16*)(ws + 71303168);   // 67,108,864 B (interleaved re/im)
  const size_t WS_NEEDED = 138412032ull;     // proven: ws >= 180 MB
  if (ws_size < WS_NEEDED) return;

  float* out0 = (float*)d_out;               // f32 [16384][1024]
  float* s_re = out0 + 16777216;             // f32 [8][2048][32][32] = Re(s)

  gemm1_naive<<<dim3(9, 4096), 256, 0, stream>>>(x, pre_w, pre_b, pre);
  u_kernel<<<2048, 256, 0, stream>>>(pre, u);
  scan_kernel<<<128, 64, 0, stream>>>(u, a, bfr, s_bf, s_re);
  gemm2_naive<<<dim3(4, 4096), 256, 0, stream>>>(s_bf, mix_w, mix_b, out0);
  ln_plain<<<16384, 64, 0, stream>>>(out0, pre);
}

// Round 12
// 420.515 us; speedup vs baseline: 10.7871x; 10.7871x over previous
//
#include <hip/hip_runtime.h>
#include <stdint.h>

typedef __attribute__((ext_vector_type(2))) __bf16 bf16x2;
typedef __attribute__((ext_vector_type(4))) __bf16 bf16x4;
typedef __attribute__((ext_vector_type(8))) __bf16 bf16x8;
typedef __attribute__((ext_vector_type(4))) float f32x4;

// ---- tiled transpose f32[K][N] -> bf16[Npad][K], zero pad rows n>=N ----
__global__ __launch_bounds__(256) void transpose_to_bf16(const float* __restrict__ src,
                                                         __bf16* __restrict__ dst,
                                                         int K, int N, int Npad) {
  __shared__ float tile[32][33];
  int n0 = blockIdx.x * 32, k0 = blockIdx.y * 32;
  int tx = threadIdx.x & 31, ty = threadIdx.x >> 5;  // ty 0..7
#pragma unroll
  for (int j = 0; j < 4; ++j) {
    int k = k0 + ty + j * 8;
    int n = n0 + tx;
    float v = 0.f;
    if (n < N) v = src[(long)k * N + n];
    tile[ty + j * 8][tx] = v;
  }
  __syncthreads();
#pragma unroll
  for (int j = 0; j < 4; ++j) {
    int n = n0 + ty + j * 8;
    int k = k0 + tx;
    if (n < Npad) dst[(long)n * K + k] = (__bf16)tile[tx][ty + j * 8];
  }
}

// ---- MFMA GEMM: C = A * Wt[N][K]^T + bias ----
// 128x128 tile, BK=32, 4 waves each 64x64 (4x4 frags of 16x16x32).
// A: f32 (reg-convert) or bf16; reg-staged + ds_write_b128; LDS stride 40.
#define LDSS 40
template <bool A_F32, bool OUT_BF16>
__global__ __launch_bounds__(256) void gemm_mfma(const void* __restrict__ Av,
                                                 const __bf16* __restrict__ Wt,
                                                 const float* __restrict__ bias,
                                                 void* __restrict__ Cout,
                                                 int K, int Nreal, int ldc) {
  __shared__ __bf16 As[128 * LDSS];
  __shared__ __bf16 Bs[128 * LDSS];
  const int tid = threadIdx.x;
  const int lane = tid & 63, wid = tid >> 6;
  const int tm = blockIdx.y * 128, tn = blockIdx.x * 128;
  const int wr = (wid >> 1) * 64, wc = (wid & 1) * 64;

  f32x4 acc[4][4] = {};

  const int q0 = tid, q1 = tid + 256;
  const int r0 = q0 >> 2, c0 = q0 & 3;
  const int r1 = q1 >> 2, c1 = q1 & 3;

  int aoff[4], boff[4];
#pragma unroll
  for (int i = 0; i < 4; ++i) {
    aoff[i] = (wr + i * 16 + (lane & 15)) * LDSS + (lane >> 4) * 8;
    boff[i] = (wc + i * 16 + (lane & 15)) * LDSS + (lane >> 4) * 8;
  }

  const float* Af = (const float*)Av;
  const __bf16* Ab = (const __bf16*)Av;
  const __bf16* Wbase = Wt + (long)tn * K;

  for (int k0 = 0; k0 < K; k0 += 32) {
    if (A_F32) {
      const float* p0 = Af + (long)(tm + r0) * K + k0 + c0 * 8;
      const float* p1 = Af + (long)(tm + r1) * K + k0 + c1 * 8;
      float4 f0 = *reinterpret_cast<const float4*>(p0);
      float4 f1 = *reinterpret_cast<const float4*>(p0 + 4);
      float4 f2 = *reinterpret_cast<const float4*>(p1);
      float4 f3 = *reinterpret_cast<const float4*>(p1 + 4);
      bf16x8 v0, v1;
      v0[0] = (__bf16)f0.x; v0[1] = (__bf16)f0.y; v0[2] = (__bf16)f0.z; v0[3] = (__bf16)f0.w;
      v0[4] = (__bf16)f1.x; v0[5] = (__bf16)f1.y; v0[6] = (__bf16)f1.z; v0[7] = (__bf16)f1.w;
      v1[0] = (__bf16)f2.x; v1[1] = (__bf16)f2.y; v1[2] = (__bf16)f2.z; v1[3] = (__bf16)f2.w;
      v1[4] = (__bf16)f3.x; v1[5] = (__bf16)f3.y; v1[6] = (__bf16)f3.z; v1[7] = (__bf16)f3.w;
      *reinterpret_cast<bf16x8*>(As + r0 * LDSS + c0 * 8) = v0;
      *reinterpret_cast<bf16x8*>(As + r1 * LDSS + c1 * 8) = v1;
    } else {
      bf16x8 a0 = *reinterpret_cast<const bf16x8*>(Ab + (long)(tm + r0) * K + k0 + c0 * 8);
      bf16x8 a1 = *reinterpret_cast<const bf16x8*>(Ab + (long)(tm + r1) * K + k0 + c1 * 8);
      *reinterpret_cast<bf16x8*>(As + r0 * LDSS + c0 * 8) = a0;
      *reinterpret_cast<bf16x8*>(As + r1 * LDSS + c1 * 8) = a1;
    }
    {
      bf16x8 w0 = *reinterpret_cast<const bf16x8*>(Wbase + (long)r0 * K + k0 + c0 * 8);
      bf16x8 w1 = *reinterpret_cast<const bf16x8*>(Wbase + (long)r1 * K + k0 + c1 * 8);
      *reinterpret_cast<bf16x8*>(Bs + r0 * LDSS + c0 * 8) = w0;
      *reinterpret_cast<bf16x8*>(Bs + r1 * LDSS + c1 * 8) = w1;
    }
    __syncthreads();
    bf16x8 af[4], bw[4];
#pragma unroll
    for (int i = 0; i < 4; ++i) af[i] = *reinterpret_cast<const bf16x8*>(&As[aoff[i]]);
#pragma unroll
    for (int i = 0; i < 4; ++i) bw[i] = *reinterpret_cast<const bf16x8*>(&Bs[boff[i]]);
#pragma unroll
    for (int mi = 0; mi < 4; ++mi)
#pragma unroll
      for (int ni = 0; ni < 4; ++ni)
        acc[mi][ni] = __builtin_amdgcn_mfma_f32_16x16x32_bf16(af[mi], bw[ni],
                                                              acc[mi][ni], 0, 0, 0);
    __syncthreads();
  }

  // epilogue: frag D row=(lane>>4)*4+r, col=lane&15
  const int rbase = tm + wr + ((lane >> 4) * 4);
  const int cbase = tn + wc + (lane & 15);
#pragma unroll
  for (int mi = 0; mi < 4; ++mi) {
#pragma unroll
    for (int ni = 0; ni < 4; ++ni) {
      int col = cbase + ni * 16;
      if (col < Nreal) {
        float bv = bias[col];
#pragma unroll
        for (int r = 0; r < 4; ++r) {
          long row = rbase + mi * 16 + r;
          float v = acc[mi][ni][r] + bv;
          if (OUT_BF16) ((__bf16*)Cout)[row * ldc + col] = (__bf16)v;
          else          ((float*)Cout)[row * ldc + col] = v;
        }
      }
    }
  }
}

// ---- u = y * sigmoid(in_gate), layout u[b][m][t] ----
__global__ __launch_bounds__(256) void u_kernel(const __bf16* __restrict__ pre,
                                                float* __restrict__ u) {
  int i = blockIdx.x * 8 + (threadIdx.x >> 5);
  int m = threadIdx.x & 31;
  const __bf16* pr = pre + (long)i * 2112;
  float y = (float)pr[m];
  float g = (float)pr[1056 + m];
  float sg = 1.f / (1.f + expf(-g));
  int b = i >> 11, t = i & 2047;
  u[(long)((b * 32) + m) * 2048 + t] = y * sg;
}

// ---- scan: interleaved bf16 (re,im) to ws + Re(s) f32 to d_out ----
__global__ __launch_bounds__(64) void scan_kernel(const float* __restrict__ u,
                                                  const float* __restrict__ a,
                                                  const float* __restrict__ bfr,
                                                  __bf16* __restrict__ s_bf,
                                                  float* __restrict__ s_re) {
  int blk = blockIdx.x;
  int b = blk >> 4, mp = blk & 15;
  int lane = threadIdx.x;
  int mh = lane >> 5, c = lane & 31;
  int m = mp * 2 + mh;
  const float* ub = u + (long)(b * 32 + m) * 2048;
  float decay = expf(-fabsf(a[m]));
  float gr = decay * cosf(bfr[c]);
  float gi = decay * sinf(bfr[c]);
  float sr = 0.f, si = 0.f;
  long base = (long)b * 2048 * 1024 + m * 32 + c;
  for (int t = 0; t < 2048; ++t) {
    float uv = ub[t];
    float nr = fmaf(gr, sr, fmaf(-gi, si, uv));
    float ni_ = fmaf(gr, si, gi * sr);
    sr = nr; si = ni_;
    long ci = base + (long)t * 1024;
    bf16x2 zv; zv[0] = (__bf16)sr; zv[1] = (__bf16)si;
    *reinterpret_cast<bf16x2*>(s_bf + 2 * ci) = zv;
    s_re[ci] = sr;
  }
}

// ---- layernorm + gated mix, in place on f32 z rows (1 wave per row) ----
__global__ __launch_bounds__(64) void ln_plain(float* __restrict__ z,
                                               const __bf16* __restrict__ pre) {
  const long row = blockIdx.x;
  float* zp = z + row * 1024;
  const int tid = threadIdx.x;
  float v[16];
  float s = 0.f, ss = 0.f;
#pragma unroll
  for (int q = 0; q < 16; ++q) {
    float x = zp[tid + q * 64];
    v[q] = x; s += x; ss += x * x;
  }
#pragma unroll
  for (int o = 32; o > 0; o >>= 1) {
    s += __shfl_down(s, o, 64);
    ss += __shfl_down(ss, o, 64);
  }
  s = __shfl(s, 0, 64);
  ss = __shfl(ss, 0, 64);
  float mean = s * (1.f / 1024.f);
  float var = ss * (1.f / 1024.f) - mean * mean;
  float rstd = rsqrtf(var + 1e-5f);
  const __bf16* pr = pre + row * 2112;
#pragma unroll
  for (int q = 0; q < 16; ++q) {
    int e = tid + q * 64;
    float th = (float)pr[32 + e];
    float og = (float)pr[1088 + e];
    float g = 1.f / (1.f + expf(-og));
    zp[e] = (v[q] - mean) * rstd * g + th * (1.f - g);
  }
}

extern "C" void kernel_launch(void* const* d_in, const int* in_sizes, int n_in,
                              void* d_out, int out_size, void* d_ws, size_t ws_size,
                              hipStream_t stream) {
  const float* x = (const float*)d_in[0];
  const float* pre_w = (const float*)d_in[1];
  const float* pre_b = (const float*)d_in[2];
  const float* mix_w = (const float*)d_in[3];
  const float* mix_b = (const float*)d_in[4];
  const float* a = (const float*)d_in[5];
  const float* bfr = (const float*)d_in[6];

  char* ws = (char*)d_ws;
  __bf16* preWT = (__bf16*)(ws + 0);           //  4,456,448 B  [2176][1024]
  __bf16* mixWT = (__bf16*)(ws + 4456448);     //  4,194,304 B  [1024][2048]
  __bf16* pre   = (__bf16*)(ws + 8650752);     // 69,206,016 B  [16384][2112]
  float*  u     = (float*)(ws + 77856768);     //  2,097,152 B
  __bf16* s_bf  = (__bf16*)(ws + 79953920);    // 67,108,864 B  interleaved re/im
  const size_t WS_NEEDED = 147062784ull;       // proven: ws >= 180 MB
  if (ws_size < WS_NEEDED) return;

  float* out0 = (float*)d_out;                 // f32 [16384][1024]
  float* s_re = out0 + 16777216;               // f32 Re(s)

  transpose_to_bf16<<<dim3(68, 32), 256, 0, stream>>>(pre_w, preWT, 1024, 2112, 2176);
  transpose_to_bf16<<<dim3(32, 64), 256, 0, stream>>>(mix_w, mixWT, 2048, 1024, 1024);
  gemm_mfma<true, true><<<dim3(17, 128), 256, 0, stream>>>(x, preWT, pre_b, pre,
                                                           1024, 2112, 2112);
  u_kernel<<<2048, 256, 0, stream>>>(pre, u);
  scan_kernel<<<128, 64, 0, stream>>>(u, a, bfr, s_bf, s_re);
  gemm_mfma<false, false><<<dim3(8, 128), 256, 0, stream>>>(s_bf, mixWT, mix_b, out0,
                                                            2048, 1024, 1024);
  ln_plain<<<16384, 64, 0, stream>>>(out0, pre);
}

// Round 13
// 384.072 us; speedup vs baseline: 11.8107x; 1.0949x over previous
//
#include <hip/hip_runtime.h>
#include <stdint.h>

typedef __attribute__((ext_vector_type(2))) __bf16 bf16x2;
typedef __attribute__((ext_vector_type(4))) __bf16 bf16x4;
typedef __attribute__((ext_vector_type(8))) __bf16 bf16x8;
typedef __attribute__((ext_vector_type(4))) float f32x4;

#define DEV __device__ __forceinline__

// async global->LDS, 16B/lane; LDS dest = wave-uniform base + lane*16 (linear)
DEV void g2lds16(const void* g, void* l) {
  __builtin_amdgcn_global_load_lds(
      (const __attribute__((address_space(1))) void*)g,
      (__attribute__((address_space(3))) void*)l, 16, 0, 0);
}

// ---- f32 -> bf16 vector convert (x) ----
__global__ __launch_bounds__(256) void cvt_f32_bf16(const float* __restrict__ s,
                                                    __bf16* __restrict__ d, int n) {
  int i = (blockIdx.x * 256 + threadIdx.x) * 4;
  if (i >= n) return;
  float4 v = *reinterpret_cast<const float4*>(s + i);
  bf16x4 o;
  o[0] = (__bf16)v.x; o[1] = (__bf16)v.y; o[2] = (__bf16)v.z; o[3] = (__bf16)v.w;
  *reinterpret_cast<bf16x4*>(d + i) = o;
}

// ---- tiled transpose f32[K][N] -> bf16[Npad][K] ----
__global__ __launch_bounds__(256) void transpose_to_bf16(const float* __restrict__ src,
                                                         __bf16* __restrict__ dst,
                                                         int K, int N, int Npad) {
  __shared__ float tile[32][33];
  int n0 = blockIdx.x * 32, k0 = blockIdx.y * 32;
  int tx = threadIdx.x & 31, ty = threadIdx.x >> 5;
#pragma unroll
  for (int j = 0; j < 4; ++j) {
    int k = k0 + ty + j * 8;
    int n = n0 + tx;
    float v = 0.f;
    if (n < N) v = src[(long)k * N + n];
    tile[ty + j * 8][tx] = v;
  }
  __syncthreads();
#pragma unroll
  for (int j = 0; j < 4; ++j) {
    int n = n0 + ty + j * 8;
    int k = k0 + tx;
    if (n < Npad) dst[(long)n * K + k] = (__bf16)tile[tx][ty + j * 8];
  }
}

// ---- MFMA GEMM (m97 structure): C = A[bf16] * Wt[N][K]^T + bias ----
// 128x128 tile, BK=32, 4 waves (64x64 each, 4x4 frags of 16x16x32).
// Both operands staged with global_load_lds width=16 into LINEAR [128][32] LDS.
template <bool OUT_BF16>
__global__ __launch_bounds__(256) void gemm_mfma(const __bf16* __restrict__ A,
                                                 const __bf16* __restrict__ Wt,
                                                 const float* __restrict__ bias,
                                                 void* __restrict__ Cout,
                                                 int K, int Nreal, int ldc) {
  __shared__ __bf16 As[128 * 32];
  __shared__ __bf16 Bs[128 * 32];
  const int tid = threadIdx.x;
  const int lane = tid & 63, wid = tid >> 6;
  const int tm = blockIdx.y * 128, tn = blockIdx.x * 128;
  const int wr = (wid >> 1) * 64, wc = (wid & 1) * 64;

  f32x4 acc[4][4] = {};

  // staging: 512 chunks of 8 bf16 (16B); thread tid -> chunks tid, tid+256.
  // chunk q: row q>>2, col (q&3)*8. LDS dest linear = chunk*16B (lane order).
  const int r0 = tid >> 2, c0 = (tid & 3) * 8;
  const int r1 = (tid + 256) >> 2, c1 = c0;

  int aoff[4], boff[4];
#pragma unroll
  for (int i = 0; i < 4; ++i) {
    aoff[i] = (wr + i * 16 + (lane & 15)) * 32 + (lane >> 4) * 8;
    boff[i] = (wc + i * 16 + (lane & 15)) * 32 + (lane >> 4) * 8;
  }

  const __bf16* Arow0 = A + (long)(tm + r0) * K + c0;
  const __bf16* Arow1 = A + (long)(tm + r1) * K + c1;
  const __bf16* Wrow0 = Wt + (long)(tn + r0) * K + c0;
  const __bf16* Wrow1 = Wt + (long)(tn + r1) * K + c1;

  for (int k0 = 0; k0 < K; k0 += 32) {
    g2lds16(Arow0 + k0, As + tid * 8);
    g2lds16(Arow1 + k0, As + (tid + 256) * 8);
    g2lds16(Wrow0 + k0, Bs + tid * 8);
    g2lds16(Wrow1 + k0, Bs + (tid + 256) * 8);
    __syncthreads();
    bf16x8 af[4], bw[4];
#pragma unroll
    for (int i = 0; i < 4; ++i) af[i] = *reinterpret_cast<const bf16x8*>(&As[aoff[i]]);
#pragma unroll
    for (int i = 0; i < 4; ++i) bw[i] = *reinterpret_cast<const bf16x8*>(&Bs[boff[i]]);
#pragma unroll
    for (int mi = 0; mi < 4; ++mi)
#pragma unroll
      for (int ni = 0; ni < 4; ++ni)
        acc[mi][ni] = __builtin_amdgcn_mfma_f32_16x16x32_bf16(af[mi], bw[ni],
                                                              acc[mi][ni], 0, 0, 0);
    __syncthreads();
  }

  // epilogue: frag D row=(lane>>4)*4+r, col=lane&15
  const int rbase = tm + wr + ((lane >> 4) * 4);
  const int cbase = tn + wc + (lane & 15);
#pragma unroll
  for (int mi = 0; mi < 4; ++mi) {
#pragma unroll
    for (int ni = 0; ni < 4; ++ni) {
      int col = cbase + ni * 16;
      if (col < Nreal) {
        float bv = bias[col];
#pragma unroll
        for (int r = 0; r < 4; ++r) {
          long row = rbase + mi * 16 + r;
          float v = acc[mi][ni][r] + bv;
          if (OUT_BF16) ((__bf16*)Cout)[row * ldc + col] = (__bf16)v;
          else          ((float*)Cout)[row * ldc + col] = v;
        }
      }
    }
  }
}

// ---- u = y * sigmoid(in_gate), layout u[b][m][t] ----
__global__ __launch_bounds__(256) void u_kernel(const __bf16* __restrict__ pre,
                                                float* __restrict__ u) {
  int i = blockIdx.x * 8 + (threadIdx.x >> 5);
  int m = threadIdx.x & 31;
  const __bf16* pr = pre + (long)i * 2112;
  float y = (float)pr[m];
  float g = (float)pr[1056 + m];
  float sg = 1.f / (1.f + expf(-g));
  int b = i >> 11, t = i & 2047;
  u[(long)((b * 32) + m) * 2048 + t] = y * sg;
}

// ---- scan: interleaved bf16 (re,im) to ws + Re(s) f32 to d_out ----
__global__ __launch_bounds__(64) void scan_kernel(const float* __restrict__ u,
                                                  const float* __restrict__ a,
                                                  const float* __restrict__ bfr,
                                                  __bf16* __restrict__ s_bf,
                                                  float* __restrict__ s_re) {
  int blk = blockIdx.x;
  int b = blk >> 4, mp = blk & 15;
  int lane = threadIdx.x;
  int mh = lane >> 5, c = lane & 31;
  int m = mp * 2 + mh;
  const float* ub = u + (long)(b * 32 + m) * 2048;
  float decay = expf(-fabsf(a[m]));
  float gr = decay * cosf(bfr[c]);
  float gi = decay * sinf(bfr[c]);
  float sr = 0.f, si = 0.f;
  long base = (long)b * 2048 * 1024 + m * 32 + c;
  for (int t = 0; t < 2048; ++t) {
    float uv = ub[t];
    float nr = fmaf(gr, sr, fmaf(-gi, si, uv));
    float ni_ = fmaf(gr, si, gi * sr);
    sr = nr; si = ni_;
    long ci = base + (long)t * 1024;
    bf16x2 zv; zv[0] = (__bf16)sr; zv[1] = (__bf16)si;
    *reinterpret_cast<bf16x2*>(s_bf + 2 * ci) = zv;
    s_re[ci] = sr;
  }
}

// ---- layernorm + gated mix, in place on f32 z rows (1 wave per row) ----
__global__ __launch_bounds__(64) void ln_plain(float* __restrict__ z,
                                               const __bf16* __restrict__ pre) {
  const long row = blockIdx.x;
  float* zp = z + row * 1024;
  const int tid = threadIdx.x;
  float v[16];
  float s = 0.f, ss = 0.f;
#pragma unroll
  for (int q = 0; q < 16; ++q) {
    float x = zp[tid + q * 64];
    v[q] = x; s += x; ss += x * x;
  }
#pragma unroll
  for (int o = 32; o > 0; o >>= 1) {
    s += __shfl_down(s, o, 64);
    ss += __shfl_down(ss, o, 64);
  }
  s = __shfl(s, 0, 64);
  ss = __shfl(ss, 0, 64);
  float mean = s * (1.f / 1024.f);
  float var = ss * (1.f / 1024.f) - mean * mean;
  float rstd = rsqrtf(var + 1e-5f);
  const __bf16* pr = pre + row * 2112;
#pragma unroll
  for (int q = 0; q < 16; ++q) {
    int e = tid + q * 64;
    float th = (float)pr[32 + e];
    float og = (float)pr[1088 + e];
    float g = 1.f / (1.f + expf(-og));
    zp[e] = (v[q] - mean) * rstd * g + th * (1.f - g);
  }
}

extern "C" void kernel_launch(void* const* d_in, const int* in_sizes, int n_in,
                              void* d_out, int out_size, void* d_ws, size_t ws_size,
                              hipStream_t stream) {
  const float* x = (const float*)d_in[0];
  const float* pre_w = (const float*)d_in[1];
  const float* pre_b = (const float*)d_in[2];
  const float* mix_w = (const float*)d_in[3];
  const float* mix_b = (const float*)d_in[4];
  const float* a = (const float*)d_in[5];
  const float* bfr = (const float*)d_in[6];

  // ws layout (147,062,784 B total — exactly the round-12-proven footprint).
  // buf0 (67MB) is x_bf during GEMM1, then s_bf after the scan (x is dead).
  char* ws = (char*)d_ws;
  __bf16* buf0  = (__bf16*)(ws + 0);           // 67,108,864 B (x_bf -> s_bf)
  __bf16* preWT = (__bf16*)(ws + 67108864);    //  4,456,448 B [2176][1024]
  __bf16* mixWT = (__bf16*)(ws + 71565312);    //  4,194,304 B [1024][2048]
  __bf16* pre   = (__bf16*)(ws + 75759616);    // 69,206,016 B [16384][2112]
  float*  u     = (float*)(ws + 144965632);    //  2,097,152 B
  const size_t WS_NEEDED = 147062784ull;       // proven in round 12
  if (ws_size < WS_NEEDED) return;

  __bf16* x_bf = buf0;
  __bf16* s_bf = buf0;

  float* out0 = (float*)d_out;                 // f32 [16384][1024]
  float* s_re = out0 + 16777216;               // f32 Re(s)

  cvt_f32_bf16<<<16384, 256, 0, stream>>>(x, x_bf, 16777216);
  transpose_to_bf16<<<dim3(68, 32), 256, 0, stream>>>(pre_w, preWT, 1024, 2112, 2176);
  transpose_to_bf16<<<dim3(32, 64), 256, 0, stream>>>(mix_w, mixWT, 2048, 1024, 1024);
  gemm_mfma<true><<<dim3(17, 128), 256, 0, stream>>>(x_bf, preWT, pre_b, pre,
                                                     1024, 2112, 2112);
  u_kernel<<<2048, 256, 0, stream>>>(pre, u);
  scan_kernel<<<128, 64, 0, stream>>>(u, a, bfr, s_bf, s_re);  // overwrites x_bf
  gemm_mfma<false><<<dim3(8, 128), 256, 0, stream>>>(s_bf, mixWT, mix_b, out0,
                                                     2048, 1024, 1024);
  ln_plain<<<16384, 64, 0, stream>>>(out0, pre);
}

// Round 14
// 383.361 us; speedup vs baseline: 11.8326x; 1.0019x over previous
//
#include <hip/hip_runtime.h>
#include <stdint.h>

typedef __attribute__((ext_vector_type(2))) __bf16 bf16x2;
typedef __attribute__((ext_vector_type(4))) __bf16 bf16x4;
typedef __attribute__((ext_vector_type(8))) __bf16 bf16x8;
typedef __attribute__((ext_vector_type(4))) float f32x4;

#define DEV __device__ __forceinline__

// async global->LDS, 16B/lane; LDS dest = wave-uniform base + lane*16 (linear)
DEV void g2lds16(const void* g, void* l) {
  __builtin_amdgcn_global_load_lds(
      (const __attribute__((address_space(1))) void*)g,
      (__attribute__((address_space(3))) void*)l, 16, 0, 0);
}

// ---- f32 -> bf16 vector convert (x) ----
__global__ __launch_bounds__(256) void cvt_f32_bf16(const float* __restrict__ s,
                                                    __bf16* __restrict__ d, int n) {
  int i = (blockIdx.x * 256 + threadIdx.x) * 4;
  if (i >= n) return;
  float4 v = *reinterpret_cast<const float4*>(s + i);
  bf16x4 o;
  o[0] = (__bf16)v.x; o[1] = (__bf16)v.y; o[2] = (__bf16)v.z; o[3] = (__bf16)v.w;
  *reinterpret_cast<bf16x4*>(d + i) = o;
}

// ---- tiled transpose f32[K][N] -> bf16[Npad][K] ----
__global__ __launch_bounds__(256) void transpose_to_bf16(const float* __restrict__ src,
                                                         __bf16* __restrict__ dst,
                                                         int K, int N, int Npad) {
  __shared__ float tile[32][33];
  int n0 = blockIdx.x * 32, k0 = blockIdx.y * 32;
  int tx = threadIdx.x & 31, ty = threadIdx.x >> 5;
#pragma unroll
  for (int j = 0; j < 4; ++j) {
    int k = k0 + ty + j * 8;
    int n = n0 + tx;
    float v = 0.f;
    if (n < N) v = src[(long)k * N + n];
    tile[ty + j * 8][tx] = v;
  }
  __syncthreads();
#pragma unroll
  for (int j = 0; j < 4; ++j) {
    int n = n0 + ty + j * 8;
    int k = k0 + tx;
    if (n < Npad) dst[(long)n * K + k] = (__bf16)tile[tx][ty + j * 8];
  }
}

// ---- MFMA GEMM, T3-minimum 2-phase: double-buffered LDS, prefetch-before-
// compute, ONE barrier per K-step. 128x128 tile, BK=32, 4 waves (64x64 each).
template <bool OUT_BF16>
__global__ __launch_bounds__(256) void gemm_mfma(const __bf16* __restrict__ A,
                                                 const __bf16* __restrict__ Wt,
                                                 const float* __restrict__ bias,
                                                 void* __restrict__ Cout,
                                                 int K, int Nreal, int ldc) {
  __shared__ __bf16 As[2][128 * 32];
  __shared__ __bf16 Bs[2][128 * 32];
  const int tid = threadIdx.x;
  const int lane = tid & 63, wid = tid >> 6;
  const int tm = blockIdx.y * 128, tn = blockIdx.x * 128;
  const int wr = (wid >> 1) * 64, wc = (wid & 1) * 64;

  f32x4 acc[4][4] = {};

  // staging: 512 chunks of 8 bf16 (16B); thread tid covers rows r0 and r0+64.
  const int r0 = tid >> 2, c0 = (tid & 3) * 8;
  const int r1 = r0 + 64;

  int aoff[4], boff[4];
#pragma unroll
  for (int i = 0; i < 4; ++i) {
    aoff[i] = (wr + i * 16 + (lane & 15)) * 32 + (lane >> 4) * 8;
    boff[i] = (wc + i * 16 + (lane & 15)) * 32 + (lane >> 4) * 8;
  }

  const __bf16* Arow0 = A + (long)(tm + r0) * K + c0;
  const __bf16* Arow1 = A + (long)(tm + r1) * K + c0;
  const __bf16* Wrow0 = Wt + (long)(tn + r0) * K + c0;
  const __bf16* Wrow1 = Wt + (long)(tn + r1) * K + c0;

  // prologue: stage tile 0 into buf 0
  g2lds16(Arow0, As[0] + tid * 8);
  g2lds16(Arow1, As[0] + (tid + 256) * 8);
  g2lds16(Wrow0, Bs[0] + tid * 8);
  g2lds16(Wrow1, Bs[0] + (tid + 256) * 8);
  __syncthreads();  // drains vmcnt(0): tile 0 resident

  const int nt = K >> 5;
  int cur = 0;
  for (int t = 1; t < nt; ++t) {
    const int k0 = t << 5;
    const int nxt = cur ^ 1;
    // issue next tile's async loads (fly during this tile's compute)
    g2lds16(Arow0 + k0, As[nxt] + tid * 8);
    g2lds16(Arow1 + k0, As[nxt] + (tid + 256) * 8);
    g2lds16(Wrow0 + k0, Bs[nxt] + tid * 8);
    g2lds16(Wrow1 + k0, Bs[nxt] + (tid + 256) * 8);
    // compute current tile
    bf16x8 af[4], bw[4];
#pragma unroll
    for (int i = 0; i < 4; ++i) af[i] = *reinterpret_cast<const bf16x8*>(&As[cur][aoff[i]]);
#pragma unroll
    for (int i = 0; i < 4; ++i) bw[i] = *reinterpret_cast<const bf16x8*>(&Bs[cur][boff[i]]);
#pragma unroll
    for (int mi = 0; mi < 4; ++mi)
#pragma unroll
      for (int ni = 0; ni < 4; ++ni)
        acc[mi][ni] = __builtin_amdgcn_mfma_f32_16x16x32_bf16(af[mi], bw[ni],
                                                              acc[mi][ni], 0, 0, 0);
    __syncthreads();  // drains vmcnt(0) (next tile ready) + read-done for cur
    cur = nxt;
  }
  // epilogue tile (no prefetch)
  {
    bf16x8 af[4], bw[4];
#pragma unroll
    for (int i = 0; i < 4; ++i) af[i] = *reinterpret_cast<const bf16x8*>(&As[cur][aoff[i]]);
#pragma unroll
    for (int i = 0; i < 4; ++i) bw[i] = *reinterpret_cast<const bf16x8*>(&Bs[cur][boff[i]]);
#pragma unroll
    for (int mi = 0; mi < 4; ++mi)
#pragma unroll
      for (int ni = 0; ni < 4; ++ni)
        acc[mi][ni] = __builtin_amdgcn_mfma_f32_16x16x32_bf16(af[mi], bw[ni],
                                                              acc[mi][ni], 0, 0, 0);
  }

  // C-write: frag D row=(lane>>4)*4+r, col=lane&15
  const int rbase = tm + wr + ((lane >> 4) * 4);
  const int cbase = tn + wc + (lane & 15);
#pragma unroll
  for (int mi = 0; mi < 4; ++mi) {
#pragma unroll
    for (int ni = 0; ni < 4; ++ni) {
      int col = cbase + ni * 16;
      if (col < Nreal) {
        float bv = bias[col];
#pragma unroll
        for (int r = 0; r < 4; ++r) {
          long row = rbase + mi * 16 + r;
          float v = acc[mi][ni][r] + bv;
          if (OUT_BF16) ((__bf16*)Cout)[row * ldc + col] = (__bf16)v;
          else          ((float*)Cout)[row * ldc + col] = v;
        }
      }
    }
  }
}

// ---- u = y * sigmoid(in_gate), layout u[b][m][t] ----
__global__ __launch_bounds__(256) void u_kernel(const __bf16* __restrict__ pre,
                                                float* __restrict__ u) {
  int i = blockIdx.x * 8 + (threadIdx.x >> 5);
  int m = threadIdx.x & 31;
  const __bf16* pr = pre + (long)i * 2112;
  float y = (float)pr[m];
  float g = (float)pr[1056 + m];
  float sg = 1.f / (1.f + expf(-g));
  int b = i >> 11, t = i & 2047;
  u[(long)((b * 32) + m) * 2048 + t] = y * sg;
}

// ---- scan: interleaved bf16 (re,im) to ws + Re(s) f32 to d_out ----
__global__ __launch_bounds__(64) void scan_kernel(const float* __restrict__ u,
                                                  const float* __restrict__ a,
                                                  const float* __restrict__ bfr,
                                                  __bf16* __restrict__ s_bf,
                                                  float* __restrict__ s_re) {
  int blk = blockIdx.x;
  int b = blk >> 4, mp = blk & 15;
  int lane = threadIdx.x;
  int mh = lane >> 5, c = lane & 31;
  int m = mp * 2 + mh;
  const float* ub = u + (long)(b * 32 + m) * 2048;
  float decay = expf(-fabsf(a[m]));
  float gr = decay * cosf(bfr[c]);
  float gi = decay * sinf(bfr[c]);
  float sr = 0.f, si = 0.f;
  long base = (long)b * 2048 * 1024 + m * 32 + c;
  for (int t = 0; t < 2048; ++t) {
    float uv = ub[t];
    float nr = fmaf(gr, sr, fmaf(-gi, si, uv));
    float ni_ = fmaf(gr, si, gi * sr);
    sr = nr; si = ni_;
    long ci = base + (long)t * 1024;
    bf16x2 zv; zv[0] = (__bf16)sr; zv[1] = (__bf16)si;
    *reinterpret_cast<bf16x2*>(s_bf + 2 * ci) = zv;
    s_re[ci] = sr;
  }
}

// ---- layernorm + gated mix, in place on f32 z rows (1 wave per row) ----
__global__ __launch_bounds__(64) void ln_plain(float* __restrict__ z,
                                               const __bf16* __restrict__ pre) {
  const long row = blockIdx.x;
  float* zp = z + row * 1024;
  const int tid = threadIdx.x;
  float v[16];
  float s = 0.f, ss = 0.f;
#pragma unroll
  for (int q = 0; q < 16; ++q) {
    float x = zp[tid + q * 64];
    v[q] = x; s += x; ss += x * x;
  }
#pragma unroll
  for (int o = 32; o > 0; o >>= 1) {
    s += __shfl_down(s, o, 64);
    ss += __shfl_down(ss, o, 64);
  }
  s = __shfl(s, 0, 64);
  ss = __shfl(ss, 0, 64);
  float mean = s * (1.f / 1024.f);
  float var = ss * (1.f / 1024.f) - mean * mean;
  float rstd = rsqrtf(var + 1e-5f);
  const __bf16* pr = pre + row * 2112;
#pragma unroll
  for (int q = 0; q < 16; ++q) {
    int e = tid + q * 64;
    float th = (float)pr[32 + e];
    float og = (float)pr[1088 + e];
    float g = 1.f / (1.f + expf(-og));
    zp[e] = (v[q] - mean) * rstd * g + th * (1.f - g);
  }
}

extern "C" void kernel_launch(void* const* d_in, const int* in_sizes, int n_in,
                              void* d_out, int out_size, void* d_ws, size_t ws_size,
                              hipStream_t stream) {
  const float* x = (const float*)d_in[0];
  const float* pre_w = (const float*)d_in[1];
  const float* pre_b = (const float*)d_in[2];
  const float* mix_w = (const float*)d_in[3];
  const float* mix_b = (const float*)d_in[4];
  const float* a = (const float*)d_in[5];
  const float* bfr = (const float*)d_in[6];

  // ws layout (147,062,784 B total — round-12/13-proven footprint).
  // buf0 (67MB) is x_bf during GEMM1, then s_bf after the scan (x is dead).
  char* ws = (char*)d_ws;
  __bf16* buf0  = (__bf16*)(ws + 0);           // 67,108,864 B (x_bf -> s_bf)
  __bf16* preWT = (__bf16*)(ws + 67108864);    //  4,456,448 B [2176][1024]
  __bf16* mixWT = (__bf16*)(ws + 71565312);    //  4,194,304 B [1024][2048]
  __bf16* pre   = (__bf16*)(ws + 75759616);    // 69,206,016 B [16384][2112]
  float*  u     = (float*)(ws + 144965632);    //  2,097,152 B
  const size_t WS_NEEDED = 147062784ull;
  if (ws_size < WS_NEEDED) return;

  __bf16* x_bf = buf0;
  __bf16* s_bf = buf0;

  float* out0 = (float*)d_out;                 // f32 [16384][1024]
  float* s_re = out0 + 16777216;               // f32 Re(s)

  cvt_f32_bf16<<<16384, 256, 0, stream>>>(x, x_bf, 16777216);
  transpose_to_bf16<<<dim3(68, 32), 256, 0, stream>>>(pre_w, preWT, 1024, 2112, 2176);
  transpose_to_bf16<<<dim3(32, 64), 256, 0, stream>>>(mix_w, mixWT, 2048, 1024, 1024);
  gemm_mfma<true><<<dim3(17, 128), 256, 0, stream>>>(x_bf, preWT, pre_b, pre,
                                                     1024, 2112, 2112);
  u_kernel<<<2048, 256, 0, stream>>>(pre, u);
  scan_kernel<<<128, 64, 0, stream>>>(u, a, bfr, s_bf, s_re);  // overwrites x_bf
  gemm_mfma<false><<<dim3(8, 128), 256, 0, stream>>>(s_bf, mixWT, mix_b, out0,
                                                     2048, 1024, 1024);
  ln_plain<<<16384, 64, 0, stream>>>(out0, pre);
}

// Round 15
// 361.317 us; speedup vs baseline: 12.5545x; 1.0610x over previous
//
#include <hip/hip_runtime.h>
#include <stdint.h>

typedef __attribute__((ext_vector_type(2))) __bf16 bf16x2;
typedef __attribute__((ext_vector_type(4))) __bf16 bf16x4;
typedef __attribute__((ext_vector_type(8))) __bf16 bf16x8;
typedef __attribute__((ext_vector_type(4))) float f32x4;

#define DEV __device__ __forceinline__

// async global->LDS, 16B/lane; LDS dest = wave-uniform base + lane*16 (linear)
DEV void g2lds16(const void* g, void* l) {
  __builtin_amdgcn_global_load_lds(
      (const __attribute__((address_space(1))) void*)g,
      (__attribute__((address_space(3))) void*)l, 16, 0, 0);
}

// ---- f32 -> bf16 vector convert (x) ----
__global__ __launch_bounds__(256) void cvt_f32_bf16(const float* __restrict__ s,
                                                    __bf16* __restrict__ d, int n) {
  int i = (blockIdx.x * 256 + threadIdx.x) * 4;
  if (i >= n) return;
  float4 v = *reinterpret_cast<const float4*>(s + i);
  bf16x4 o;
  o[0] = (__bf16)v.x; o[1] = (__bf16)v.y; o[2] = (__bf16)v.z; o[3] = (__bf16)v.w;
  *reinterpret_cast<bf16x4*>(d + i) = o;
}

// ---- tiled transpose f32[K][N] -> bf16[Npad][K] ----
__global__ __launch_bounds__(256) void transpose_to_bf16(const float* __restrict__ src,
                                                         __bf16* __restrict__ dst,
                                                         int K, int N, int Npad) {
  __shared__ float tile[32][33];
  int n0 = blockIdx.x * 32, k0 = blockIdx.y * 32;
  int tx = threadIdx.x & 31, ty = threadIdx.x >> 5;
#pragma unroll
  for (int j = 0; j < 4; ++j) {
    int k = k0 + ty + j * 8;
    int n = n0 + tx;
    float v = 0.f;
    if (n < N) v = src[(long)k * N + n];
    tile[ty + j * 8][tx] = v;
  }
  __syncthreads();
#pragma unroll
  for (int j = 0; j < 4; ++j) {
    int n = n0 + ty + j * 8;
    int k = k0 + tx;
    if (n < Npad) dst[(long)n * K + k] = (__bf16)tile[tx][ty + j * 8];
  }
}

// ---- MFMA GEMM, 2-phase dbuf + XCD-chunked block swizzle (T1) ----
// 128x128 tile, BK=32, 4 waves (64x64 each). nwg must be divisible by 8.
template <bool OUT_BF16>
__global__ __launch_bounds__(256) void gemm_mfma(const __bf16* __restrict__ A,
                                                 const __bf16* __restrict__ Wt,
                                                 const float* __restrict__ bias,
                                                 void* __restrict__ Cout,
                                                 int K, int Nreal, int ldc) {
  __shared__ __bf16 As[2][128 * 32];
  __shared__ __bf16 Bs[2][128 * 32];
  const int tid = threadIdx.x;
  const int lane = tid & 63, wid = tid >> 6;

  // T1: XCD-chunked bijective swizzle. HW assigns orig%8 -> XCD; give each
  // XCD a contiguous band of logical tiles (A-panel locality per XCD-L2).
  const int nwg = gridDim.x * gridDim.y;
  const int orig = blockIdx.y * gridDim.x + blockIdx.x;
  const int wg = ((orig & 7) * (nwg >> 3)) + (orig >> 3);
  const int tm = (wg / gridDim.x) * 128, tn = (wg % gridDim.x) * 128;

  const int wr = (wid >> 1) * 64, wc = (wid & 1) * 64;

  f32x4 acc[4][4] = {};

  const int r0 = tid >> 2, c0 = (tid & 3) * 8;
  const int r1 = r0 + 64;

  int aoff[4], boff[4];
#pragma unroll
  for (int i = 0; i < 4; ++i) {
    aoff[i] = (wr + i * 16 + (lane & 15)) * 32 + (lane >> 4) * 8;
    boff[i] = (wc + i * 16 + (lane & 15)) * 32 + (lane >> 4) * 8;
  }

  const __bf16* Arow0 = A + (long)(tm + r0) * K + c0;
  const __bf16* Arow1 = A + (long)(tm + r1) * K + c0;
  const __bf16* Wrow0 = Wt + (long)(tn + r0) * K + c0;
  const __bf16* Wrow1 = Wt + (long)(tn + r1) * K + c0;

  g2lds16(Arow0, As[0] + tid * 8);
  g2lds16(Arow1, As[0] + (tid + 256) * 8);
  g2lds16(Wrow0, Bs[0] + tid * 8);
  g2lds16(Wrow1, Bs[0] + (tid + 256) * 8);
  __syncthreads();

  const int nt = K >> 5;
  int cur = 0;
  for (int t = 1; t < nt; ++t) {
    const int k0 = t << 5;
    const int nxt = cur ^ 1;
    g2lds16(Arow0 + k0, As[nxt] + tid * 8);
    g2lds16(Arow1 + k0, As[nxt] + (tid + 256) * 8);
    g2lds16(Wrow0 + k0, Bs[nxt] + tid * 8);
    g2lds16(Wrow1 + k0, Bs[nxt] + (tid + 256) * 8);
    bf16x8 af[4], bw[4];
#pragma unroll
    for (int i = 0; i < 4; ++i) af[i] = *reinterpret_cast<const bf16x8*>(&As[cur][aoff[i]]);
#pragma unroll
    for (int i = 0; i < 4; ++i) bw[i] = *reinterpret_cast<const bf16x8*>(&Bs[cur][boff[i]]);
#pragma unroll
    for (int mi = 0; mi < 4; ++mi)
#pragma unroll
      for (int ni = 0; ni < 4; ++ni)
        acc[mi][ni] = __builtin_amdgcn_mfma_f32_16x16x32_bf16(af[mi], bw[ni],
                                                              acc[mi][ni], 0, 0, 0);
    __syncthreads();
    cur = nxt;
  }
  {
    bf16x8 af[4], bw[4];
#pragma unroll
    for (int i = 0; i < 4; ++i) af[i] = *reinterpret_cast<const bf16x8*>(&As[cur][aoff[i]]);
#pragma unroll
    for (int i = 0; i < 4; ++i) bw[i] = *reinterpret_cast<const bf16x8*>(&Bs[cur][boff[i]]);
#pragma unroll
    for (int mi = 0; mi < 4; ++mi)
#pragma unroll
      for (int ni = 0; ni < 4; ++ni)
        acc[mi][ni] = __builtin_amdgcn_mfma_f32_16x16x32_bf16(af[mi], bw[ni],
                                                              acc[mi][ni], 0, 0, 0);
  }

  const int rbase = tm + wr + ((lane >> 4) * 4);
  const int cbase = tn + wc + (lane & 15);
#pragma unroll
  for (int mi = 0; mi < 4; ++mi) {
#pragma unroll
    for (int ni = 0; ni < 4; ++ni) {
      int col = cbase + ni * 16;
      if (col < Nreal) {
        float bv = bias[col];
#pragma unroll
        for (int r = 0; r < 4; ++r) {
          long row = rbase + mi * 16 + r;
          float v = acc[mi][ni][r] + bv;
          if (OUT_BF16) ((__bf16*)Cout)[row * ldc + col] = (__bf16)v;
          else          ((float*)Cout)[row * ldc + col] = v;
        }
      }
    }
  }
}

// ---- u = y * sigmoid(in_gate), layout u[b][m][t] ----
__global__ __launch_bounds__(256) void u_kernel(const __bf16* __restrict__ pre,
                                                float* __restrict__ u) {
  int i = blockIdx.x * 8 + (threadIdx.x >> 5);
  int m = threadIdx.x & 31;
  const __bf16* pr = pre + (long)i * 2112;
  float y = (float)pr[m];
  float g = (float)pr[1056 + m];
  float sg = 1.f / (1.f + expf(-g));
  int b = i >> 11, t = i & 2047;
  u[(long)((b * 32) + m) * 2048 + t] = y * sg;
}

// ---- scan: interleaved bf16 (re,im) to ws + Re(s) f32 to d_out ----
__global__ __launch_bounds__(64) void scan_kernel(const float* __restrict__ u,
                                                  const float* __restrict__ a,
                                                  const float* __restrict__ bfr,
                                                  __bf16* __restrict__ s_bf,
                                                  float* __restrict__ s_re) {
  int blk = blockIdx.x;
  int b = blk >> 4, mp = blk & 15;
  int lane = threadIdx.x;
  int mh = lane >> 5, c = lane & 31;
  int m = mp * 2 + mh;
  const float* ub = u + (long)(b * 32 + m) * 2048;
  float decay = expf(-fabsf(a[m]));
  float gr = decay * cosf(bfr[c]);
  float gi = decay * sinf(bfr[c]);
  float sr = 0.f, si = 0.f;
  long base = (long)b * 2048 * 1024 + m * 32 + c;
  for (int t = 0; t < 2048; ++t) {
    float uv = ub[t];
    float nr = fmaf(gr, sr, fmaf(-gi, si, uv));
    float ni_ = fmaf(gr, si, gi * sr);
    sr = nr; si = ni_;
    long ci = base + (long)t * 1024;
    bf16x2 zv; zv[0] = (__bf16)sr; zv[1] = (__bf16)si;
    *reinterpret_cast<bf16x2*>(s_bf + 2 * ci) = zv;
    s_re[ci] = sr;
  }
}

// ---- layernorm + gated mix: vectorized (float4 z, bf16x4 th/og), in place ----
__global__ __launch_bounds__(256) void ln_gate_kernel(float* __restrict__ z,
                                                      const __bf16* __restrict__ pre) {
  __shared__ float rs[4], rss[4];
  long row = blockIdx.x;
  float* zp = z + row * 1024;
  int tid = threadIdx.x;
  float4 v = *reinterpret_cast<const float4*>(zp + tid * 4);
  float s = v.x + v.y + v.z + v.w;
  float ss = v.x * v.x + v.y * v.y + v.z * v.z + v.w * v.w;
#pragma unroll
  for (int o = 32; o > 0; o >>= 1) {
    s += __shfl_down(s, o, 64);
    ss += __shfl_down(ss, o, 64);
  }
  if ((tid & 63) == 0) { rs[tid >> 6] = s; rss[tid >> 6] = ss; }
  __syncthreads();
  s = rs[0] + rs[1] + rs[2] + rs[3];
  ss = rss[0] + rss[1] + rss[2] + rss[3];
  float mean = s * (1.f / 1024.f);
  float var = ss * (1.f / 1024.f) - mean * mean;
  float rstd = rsqrtf(var + 1e-5f);
  const __bf16* pr = pre + row * 2112;
  bf16x4 th = *reinterpret_cast<const bf16x4*>(pr + 32 + tid * 4);
  bf16x4 og = *reinterpret_cast<const bf16x4*>(pr + 1088 + tid * 4);
  float4 o; float g;
  g = 1.f / (1.f + expf(-(float)og[0])); o.x = (v.x - mean) * rstd * g + (float)th[0] * (1.f - g);
  g = 1.f / (1.f + expf(-(float)og[1])); o.y = (v.y - mean) * rstd * g + (float)th[1] * (1.f - g);
  g = 1.f / (1.f + expf(-(float)og[2])); o.z = (v.z - mean) * rstd * g + (float)th[2] * (1.f - g);
  g = 1.f / (1.f + expf(-(float)og[3])); o.w = (v.w - mean) * rstd * g + (float)th[3] * (1.f - g);
  *reinterpret_cast<float4*>(zp + tid * 4) = o;
}

extern "C" void kernel_launch(void* const* d_in, const int* in_sizes, int n_in,
                              void* d_out, int out_size, void* d_ws, size_t ws_size,
                              hipStream_t stream) {
  const float* x = (const float*)d_in[0];
  const float* pre_w = (const float*)d_in[1];
  const float* pre_b = (const float*)d_in[2];
  const float* mix_w = (const float*)d_in[3];
  const float* mix_b = (const float*)d_in[4];
  const float* a = (const float*)d_in[5];
  const float* bfr = (const float*)d_in[6];

  // ws layout (147,062,784 B — proven footprint). buf0 = x_bf then s_bf.
  char* ws = (char*)d_ws;
  __bf16* buf0  = (__bf16*)(ws + 0);           // 67,108,864 B (x_bf -> s_bf)
  __bf16* preWT = (__bf16*)(ws + 67108864);    //  4,456,448 B [2176][1024]
  __bf16* mixWT = (__bf16*)(ws + 71565312);    //  4,194,304 B [1024][2048]
  __bf16* pre   = (__bf16*)(ws + 75759616);    // 69,206,016 B [16384][2112]
  float*  u     = (float*)(ws + 144965632);    //  2,097,152 B
  const size_t WS_NEEDED = 147062784ull;
  if (ws_size < WS_NEEDED) return;

  __bf16* x_bf = buf0;
  __bf16* s_bf = buf0;

  float* out0 = (float*)d_out;                 // f32 [16384][1024]
  float* s_re = out0 + 16777216;               // f32 Re(s)

  cvt_f32_bf16<<<16384, 256, 0, stream>>>(x, x_bf, 16777216);
  transpose_to_bf16<<<dim3(68, 32), 256, 0, stream>>>(pre_w, preWT, 1024, 2112, 2176);
  transpose_to_bf16<<<dim3(32, 64), 256, 0, stream>>>(mix_w, mixWT, 2048, 1024, 1024);
  gemm_mfma<true><<<dim3(17, 128), 256, 0, stream>>>(x_bf, preWT, pre_b, pre,
                                                     1024, 2112, 2112);
  u_kernel<<<2048, 256, 0, stream>>>(pre, u);
  scan_kernel<<<128, 64, 0, stream>>>(u, a, bfr, s_bf, s_re);  // overwrites x_bf
  gemm_mfma<false><<<dim3(8, 128), 256, 0, stream>>>(s_bf, mixWT, mix_b, out0,
                                                     2048, 1024, 1024);
  ln_gate_kernel<<<16384, 256, 0, stream>>>(out0, pre);
}

// Round 16
// 339.865 us; speedup vs baseline: 13.3469x; 1.0631x over previous
//
#include <hip/hip_runtime.h>
#include <stdint.h>

typedef __attribute__((ext_vector_type(2))) __bf16 bf16x2;
typedef __attribute__((ext_vector_type(4))) __bf16 bf16x4;
typedef __attribute__((ext_vector_type(8))) __bf16 bf16x8;
typedef __attribute__((ext_vector_type(4))) float f32x4;

#define DEV __device__ __forceinline__

// async global->LDS, 16B/lane; LDS dest = wave-uniform base + lane*16 (linear)
DEV void g2lds16(const void* g, void* l) {
  __builtin_amdgcn_global_load_lds(
      (const __attribute__((address_space(1))) void*)g,
      (__attribute__((address_space(3))) void*)l, 16, 0, 0);
}

// raw workgroup barrier with compiler memory fence (raw s_barrier is IntrNoMem;
// the asm "memory" clobbers stop the compiler moving LDS ops across it)
DEV void barrier_ws() {
  __builtin_amdgcn_sched_barrier(0);
  asm volatile("" ::: "memory");
  __builtin_amdgcn_s_barrier();
  asm volatile("" ::: "memory");
  __builtin_amdgcn_sched_barrier(0);
}

// ---- f32 -> bf16 vector convert (x) ----
__global__ __launch_bounds__(256) void cvt_f32_bf16(const float* __restrict__ s,
                                                    __bf16* __restrict__ d, int n) {
  int i = (blockIdx.x * 256 + threadIdx.x) * 4;
  if (i >= n) return;
  float4 v = *reinterpret_cast<const float4*>(s + i);
  bf16x4 o;
  o[0] = (__bf16)v.x; o[1] = (__bf16)v.y; o[2] = (__bf16)v.z; o[3] = (__bf16)v.w;
  *reinterpret_cast<bf16x4*>(d + i) = o;
}

// ---- tiled transpose f32[K][N] -> bf16[Npad][K] ----
__global__ __launch_bounds__(256) void transpose_to_bf16(const float* __restrict__ src,
                                                         __bf16* __restrict__ dst,
                                                         int K, int N, int Npad) {
  __shared__ float tile[32][33];
  int n0 = blockIdx.x * 32, k0 = blockIdx.y * 32;
  int tx = threadIdx.x & 31, ty = threadIdx.x >> 5;
#pragma unroll
  for (int j = 0; j < 4; ++j) {
    int k = k0 + ty + j * 8;
    int n = n0 + tx;
    float v = 0.f;
    if (n < N) v = src[(long)k * N + n];
    tile[ty + j * 8][tx] = v;
  }
  __syncthreads();
#pragma unroll
  for (int j = 0; j < 4; ++j) {
    int n = n0 + ty + j * 8;
    int k = k0 + tx;
    if (n < Npad) dst[(long)n * K + k] = (__bf16)tile[tx][ty + j * 8];
  }
}

// ============================================================================
// 256x256 8-phase MFMA GEMM (T1+T3+T4+T5). BK=64 split into two 16KB K-halves.
// 8 waves (2M x 4N), per-wave 128x64 output = acc[8][4] f32x4.
// LDS 128KB: A,B each 2(dbuf) x 2(k-half) x 256x32 bf16, slot-swizzled.
// Slot map (per 16KB half, 1024 slots of 16B): slot(row,c) =
//   (row>>1)*8 + (row&1)*4 + ((c + (row>>1)) & 3)   [bijective; 2-way banks]
// Stage: thread tid loads q = {tid, tid+512}: row = 2*(q>>3) | ((q>>2)&1),
//   c = ((q&3) - (q>>3)) & 3  -> linear gload_lds dest slot q.
// Schedule/K-tile: phases (mq,kh) = (0,0)(1,0)(0,1)(1,1); stage next tile's
//   halves A0,B0,A1,B1 at phases 1..4; vmcnt(4) at ends of phases 2 and 4.
// ============================================================================
#define STAGE_A(d, kh, kc)                                           \
  { g2lds16(A + aoffg0 + (kc), &As[d][(kh)*8192 + q0 * 8]);          \
    g2lds16(A + aoffg1 + (kc), &As[d][(kh)*8192 + q1 * 8]); }
#define STAGE_B(d, kh, kc)                                           \
  { g2lds16(Wt + boffg0 + (kc), &Bs[d][(kh)*8192 + q0 * 8]);         \
    g2lds16(Wt + boffg1 + (kc), &Bs[d][(kh)*8192 + q1 * 8]); }

#define PHASE(d, MQ, KH, READB, STAGE_STMT, TAILWAIT)                         \
  {                                                                           \
    bf16x8 af[4];                                                             \
    _Pragma("unroll") for (int i = 0; i < 4; ++i)                             \
        af[i] = *reinterpret_cast<const bf16x8*>(                             \
            &As[d][(KH)*8192 + aoffl[(MQ)*4 + i]]);                           \
    if (READB) {                                                              \
      _Pragma("unroll") for (int n = 0; n < 4; ++n)                           \
          bw[n] = *reinterpret_cast<const bf16x8*>(                           \
              &Bs[d][(KH)*8192 + boffl[n]]);                                  \
    }                                                                         \
    STAGE_STMT;                                                               \
    barrier_ws();                                                             \
    __builtin_amdgcn_s_setprio(1);                                            \
    _Pragma("unroll") for (int i = 0; i < 4; ++i)                             \
      _Pragma("unroll") for (int n = 0; n < 4; ++n)                           \
          acc[(MQ)*4 + i][n] = __builtin_amdgcn_mfma_f32_16x16x32_bf16(       \
              af[i], bw[n], acc[(MQ)*4 + i][n], 0, 0, 0);                     \
    __builtin_amdgcn_s_setprio(0);                                            \
    TAILWAIT;                                                                 \
    barrier_ws();                                                             \
  }

template <bool OUT_BF16>
__global__ __launch_bounds__(512, 2) void gemm_8p(const __bf16* __restrict__ A,
                                                  const __bf16* __restrict__ Wt,
                                                  const float* __restrict__ bias,
                                                  void* __restrict__ Cout,
                                                  int K, int Nreal, int ldc,
                                                  int gx) {
  __shared__ __bf16 As[2][16384];
  __shared__ __bf16 Bs[2][16384];
  const int tid = threadIdx.x;
  const int lane = tid & 63, wid = tid >> 6;
  const int wr = wid >> 2, wc = wid & 3;  // 2 x 4 waves

  // T1: XCD-chunked bijective swizzle (gridDim.x % 8 == 0)
  const int nwg = gridDim.x;
  const int orig = blockIdx.x;
  const int wg = ((orig & 7) * (nwg >> 3)) + (orig >> 3);
  const int tm = (wg / gx) * 256, tn = (wg % gx) * 256;

  f32x4 acc[8][4] = {};
  bf16x8 bw[4];

  // staging decode
  const int q0 = tid, q1 = tid + 512;
  const int row0 = ((q0 >> 3) << 1) | ((q0 >> 2) & 1);
  const int c0e = (((q0 & 3) - (q0 >> 3)) & 3) * 8;
  const int row1 = ((q1 >> 3) << 1) | ((q1 >> 2) & 1);
  const int c1e = (((q1 & 3) - (q1 >> 3)) & 3) * 8;
  const long aoffg0 = (long)(tm + row0) * K + c0e;
  const long aoffg1 = (long)(tm + row1) * K + c1e;
  const long boffg0 = (long)(tn + row0) * K + c0e;
  const long boffg1 = (long)(tn + row1) * K + c1e;

  // per-lane read offsets (elements within a 16KB k-half)
  const int l15 = lane & 15, cl = lane >> 4;
  int aoffl[8], boffl[4];
#pragma unroll
  for (int mf = 0; mf < 8; ++mf) {
    int row = wr * 128 + (mf >> 2) * 64 + (mf & 3) * 16 + l15;
    aoffl[mf] = (row >> 1) * 64 + (((row & 1) << 2) | ((cl + (row >> 1)) & 3)) * 8;
  }
#pragma unroll
  for (int nf = 0; nf < 4; ++nf) {
    int row = wc * 64 + nf * 16 + l15;
    boffl[nf] = (row >> 1) * 64 + (((row & 1) << 2) | ((cl + (row >> 1)) & 3)) * 8;
  }

  // prologue: stage K-tile 0 (A0,B0,A1,B1) into buf 0
  STAGE_A(0, 0, 0);
  STAGE_B(0, 0, 0);
  STAGE_A(0, 1, 32);
  STAGE_B(0, 1, 32);
  asm volatile("s_waitcnt vmcnt(4)" ::: "memory");  // A0,B0 resident
  barrier_ws();

  const int nt = K >> 6;
  for (int T = 0; T < nt - 1; ++T) {
    const int d = T & 1, e = d ^ 1;
    const int kc = (T + 1) << 6;
    PHASE(d, 0, 0, 1, STAGE_A(e, 0, kc), ((void)0));
    PHASE(d, 1, 0, 0, STAGE_B(e, 0, kc),
          asm volatile("s_waitcnt vmcnt(4)" ::: "memory"));
    PHASE(d, 0, 1, 1, STAGE_A(e, 1, kc + 32), ((void)0));
    PHASE(d, 1, 1, 0, STAGE_B(e, 1, kc + 32),
          asm volatile("s_waitcnt vmcnt(4)" ::: "memory"));
  }
  {  // tail K-tile: no stages; drain before k-half 1 reads
    const int d = (nt - 1) & 1;
    PHASE(d, 0, 0, 1, ((void)0), ((void)0));
    PHASE(d, 1, 0, 0, ((void)0),
          asm volatile("s_waitcnt vmcnt(0)" ::: "memory"));
    PHASE(d, 0, 1, 1, ((void)0), ((void)0));
    PHASE(d, 1, 1, 0, ((void)0), ((void)0));
  }

  // epilogue: frag D row=(lane>>4)*4+r, col=lane&15
#pragma unroll
  for (int mf = 0; mf < 8; ++mf) {
    const int rg = tm + wr * 128 + (mf >> 2) * 64 + (mf & 3) * 16 + (lane >> 4) * 4;
#pragma unroll
    for (int nf = 0; nf < 4; ++nf) {
      int col = tn + wc * 64 + nf * 16 + l15;
      if (col < Nreal) {
        float bv = bias[col];
#pragma unroll
        for (int r = 0; r < 4; ++r) {
          long row = rg + r;
          float v = acc[mf][nf][r] + bv;
          if (OUT_BF16) ((__bf16*)Cout)[row * (long)ldc + col] = (__bf16)v;
          else          ((float*)Cout)[row * (long)ldc + col] = v;
        }
      }
    }
  }
}

// ---- u = y * sigmoid(in_gate), layout u[b][m][t] ----
__global__ __launch_bounds__(256) void u_kernel(const __bf16* __restrict__ pre,
                                                float* __restrict__ u) {
  int i = blockIdx.x * 8 + (threadIdx.x >> 5);
  int m = threadIdx.x & 31;
  const __bf16* pr = pre + (long)i * 2112;
  float y = (float)pr[m];
  float g = (float)pr[1056 + m];
  float sg = 1.f / (1.f + expf(-g));
  int b = i >> 11, t = i & 2047;
  u[(long)((b * 32) + m) * 2048 + t] = y * sg;
}

// ---- scan: interleaved bf16 (re,im) to ws + Re(s) f32 to d_out ----
__global__ __launch_bounds__(64) void scan_kernel(const float* __restrict__ u,
                                                  const float* __restrict__ a,
                                                  const float* __restrict__ bfr,
                                                  __bf16* __restrict__ s_bf,
                                                  float* __restrict__ s_re) {
  int blk = blockIdx.x;
  int b = blk >> 4, mp = blk & 15;
  int lane = threadIdx.x;
  int mh = lane >> 5, c = lane & 31;
  int m = mp * 2 + mh;
  const float* ub = u + (long)(b * 32 + m) * 2048;
  float decay = expf(-fabsf(a[m]));
  float gr = decay * cosf(bfr[c]);
  float gi = decay * sinf(bfr[c]);
  float sr = 0.f, si = 0.f;
  long base = (long)b * 2048 * 1024 + m * 32 + c;
  for (int t = 0; t < 2048; ++t) {
    float uv = ub[t];
    float nr = fmaf(gr, sr, fmaf(-gi, si, uv));
    float ni_ = fmaf(gr, si, gi * sr);
    sr = nr; si = ni_;
    long ci = base + (long)t * 1024;
    bf16x2 zv; zv[0] = (__bf16)sr; zv[1] = (__bf16)si;
    *reinterpret_cast<bf16x2*>(s_bf + 2 * ci) = zv;
    s_re[ci] = sr;
  }
}

// ---- layernorm + gated mix: vectorized, in place on f32 z rows ----
__global__ __launch_bounds__(256) void ln_gate_kernel(float* __restrict__ z,
                                                      const __bf16* __restrict__ pre) {
  __shared__ float rs[4], rss[4];
  long row = blockIdx.x;
  float* zp = z + row * 1024;
  int tid = threadIdx.x;
  float4 v = *reinterpret_cast<const float4*>(zp + tid * 4);
  float s = v.x + v.y + v.z + v.w;
  float ss = v.x * v.x + v.y * v.y + v.z * v.z + v.w * v.w;
#pragma unroll
  for (int o = 32; o > 0; o >>= 1) {
    s += __shfl_down(s, o, 64);
    ss += __shfl_down(ss, o, 64);
  }
  if ((tid & 63) == 0) { rs[tid >> 6] = s; rss[tid >> 6] = ss; }
  __syncthreads();
  s = rs[0] + rs[1] + rs[2] + rs[3];
  ss = rss[0] + rss[1] + rss[2] + rss[3];
  float mean = s * (1.f / 1024.f);
  float var = ss * (1.f / 1024.f) - mean * mean;
  float rstd = rsqrtf(var + 1e-5f);
  const __bf16* pr = pre + row * 2112;
  bf16x4 th = *reinterpret_cast<const bf16x4*>(pr + 32 + tid * 4);
  bf16x4 og = *reinterpret_cast<const bf16x4*>(pr + 1088 + tid * 4);
  float4 o; float g;
  g = 1.f / (1.f + expf(-(float)og[0])); o.x = (v.x - mean) * rstd * g + (float)th[0] * (1.f - g);
  g = 1.f / (1.f + expf(-(float)og[1])); o.y = (v.y - mean) * rstd * g + (float)th[1] * (1.f - g);
  g = 1.f / (1.f + expf(-(float)og[2])); o.z = (v.z - mean) * rstd * g + (float)th[2] * (1.f - g);
  g = 1.f / (1.f + expf(-(float)og[3])); o.w = (v.w - mean) * rstd * g + (float)th[3] * (1.f - g);
  *reinterpret_cast<float4*>(zp + tid * 4) = o;
}

extern "C" void kernel_launch(void* const* d_in, const int* in_sizes, int n_in,
                              void* d_out, int out_size, void* d_ws, size_t ws_size,
                              hipStream_t stream) {
  const float* x = (const float*)d_in[0];
  const float* pre_w = (const float*)d_in[1];
  const float* pre_b = (const float*)d_in[2];
  const float* mix_w = (const float*)d_in[3];
  const float* mix_b = (const float*)d_in[4];
  const float* a = (const float*)d_in[5];
  const float* bfr = (const float*)d_in[6];

  // ws: buf0 (x_bf -> s_bf) | wtbuf (preWT then mixWT, sequential) | pre | u
  char* ws = (char*)d_ws;
  __bf16* buf0  = (__bf16*)(ws + 0);           // 67,108,864 B
  __bf16* wtbuf = (__bf16*)(ws + 67108864);    //  4,718,592 B [2304][1024] max
  __bf16* pre   = (__bf16*)(ws + 71827456);    // 69,206,016 B [16384][2112]
  float*  u     = (float*)(ws + 141033472);    //  2,097,152 B
  const size_t WS_NEEDED = 143130624ull;       // < proven 147,062,784
  if (ws_size < WS_NEEDED) return;

  __bf16* x_bf = buf0;
  __bf16* s_bf = buf0;

  float* out0 = (float*)d_out;                 // f32 [16384][1024]
  float* s_re = out0 + 16777216;               // f32 Re(s)

  cvt_f32_bf16<<<16384, 256, 0, stream>>>(x, x_bf, 16777216);
  transpose_to_bf16<<<dim3(72, 32), 256, 0, stream>>>(pre_w, wtbuf, 1024, 2112, 2304);
  gemm_8p<true><<<576, 512, 0, stream>>>(x_bf, wtbuf, pre_b, pre, 1024, 2112, 2112, 9);
  u_kernel<<<2048, 256, 0, stream>>>(pre, u);
  transpose_to_bf16<<<dim3(32, 64), 256, 0, stream>>>(mix_w, wtbuf, 2048, 1024, 1024);
  scan_kernel<<<128, 64, 0, stream>>>(u, a, bfr, s_bf, s_re);  // overwrites x_bf
  gemm_8p<false><<<256, 512, 0, stream>>>(s_bf, wtbuf, mix_b, out0, 2048, 1024, 1024, 4);
  ln_gate_kernel<<<16384, 256, 0, stream>>>(out0, pre);
}

// Round 17
// 325.814 us; speedup vs baseline: 13.9225x; 1.0431x over previous
//
#include <hip/hip_runtime.h>
#include <stdint.h>

typedef __attribute__((ext_vector_type(2))) __bf16 bf16x2;
typedef __attribute__((ext_vector_type(4))) __bf16 bf16x4;
typedef __attribute__((ext_vector_type(8))) __bf16 bf16x8;
typedef __attribute__((ext_vector_type(4))) float f32x4;

#define DEV __device__ __forceinline__

// async global->LDS, 16B/lane; LDS dest = wave-uniform base + lane*16 (linear)
DEV void g2lds16(const void* g, void* l) {
  __builtin_amdgcn_global_load_lds(
      (const __attribute__((address_space(1))) void*)g,
      (__attribute__((address_space(3))) void*)l, 16, 0, 0);
}

// raw barrier with compiler memory fence (no vmcnt/lgkmcnt drain)
DEV void bar() {
  asm volatile("" ::: "memory");
  __builtin_amdgcn_s_barrier();
  asm volatile("" ::: "memory");
}
DEV void vm4() { asm volatile("s_waitcnt vmcnt(4)" ::: "memory"); }
DEV void vm0() { asm volatile("s_waitcnt vmcnt(0)" ::: "memory"); }

// ---- f32 -> bf16 vector convert (x) ----
__global__ __launch_bounds__(256) void cvt_f32_bf16(const float* __restrict__ s,
                                                    __bf16* __restrict__ d, int n) {
  int i = (blockIdx.x * 256 + threadIdx.x) * 4;
  if (i >= n) return;
  float4 v = *reinterpret_cast<const float4*>(s + i);
  bf16x4 o;
  o[0] = (__bf16)v.x; o[1] = (__bf16)v.y; o[2] = (__bf16)v.z; o[3] = (__bf16)v.w;
  *reinterpret_cast<bf16x4*>(d + i) = o;
}

// ---- tiled transpose f32[K][N] -> bf16[Npad][K] ----
__global__ __launch_bounds__(256) void transpose_to_bf16(const float* __restrict__ src,
                                                         __bf16* __restrict__ dst,
                                                         int K, int N, int Npad) {
  __shared__ float tile[32][33];
  int n0 = blockIdx.x * 32, k0 = blockIdx.y * 32;
  int tx = threadIdx.x & 31, ty = threadIdx.x >> 5;
#pragma unroll
  for (int j = 0; j < 4; ++j) {
    int k = k0 + ty + j * 8;
    int n = n0 + tx;
    float v = 0.f;
    if (n < N) v = src[(long)k * N + n];
    tile[ty + j * 8][tx] = v;
  }
  __syncthreads();
#pragma unroll
  for (int j = 0; j < 4; ++j) {
    int n = n0 + ty + j * 8;
    int k = k0 + tx;
    if (n < Npad) dst[(long)n * K + k] = (__bf16)tile[tx][ty + j * 8];
  }
}

// ============================================================================
// 256x256 MFMA GEMM, 2-barriers-per-K-tile pipelined schedule.
// BK=64 = two 16KB K-halves per operand. 8 waves (2M x 4N), wave 128x64.
// LDS 128KB, slot-swizzled (bijective, 2-way banks = free).
// Certification: vmcnt(4)+barrier certifies one K-half for ALL waves
// (vmcnt is per-wave; only a barrier after everyone's vmcnt certifies the
// collectively-staged tile). Operand ds_reads issue right after their
// certifying barrier (or a full MFMA-block early when already certified),
// so read latency hides under MFMA / barrier wait.
// ============================================================================
#define STAGE_A(e, kh, kc)                                           \
  { g2lds16(A + aoffg0 + (kc), &As[e][(kh)*8192 + q0 * 8]);          \
    g2lds16(A + aoffg1 + (kc), &As[e][(kh)*8192 + q1 * 8]); }
#define STAGE_B(e, kh, kc)                                           \
  { g2lds16(Wt + boffg0 + (kc), &Bs[e][(kh)*8192 + q0 * 8]);         \
    g2lds16(Wt + boffg1 + (kc), &Bs[e][(kh)*8192 + q1 * 8]); }

#define READ_A(dst, MQ, KH, D)                                       \
  _Pragma("unroll") for (int i = 0; i < 4; ++i)                      \
      dst[i] = *reinterpret_cast<const bf16x8*>(                     \
          &As[D][(KH)*8192 + aoffl[(MQ)*4 + i]]);
#define READ_B(dst, KH, D)                                           \
  _Pragma("unroll") for (int n = 0; n < 4; ++n)                      \
      dst[n] = *reinterpret_cast<const bf16x8*>(                     \
          &Bs[D][(KH)*8192 + boffl[n]]);

#define MFMA_BLK(MQ, AF, BW)                                                  \
  __builtin_amdgcn_s_setprio(1);                                              \
  _Pragma("unroll") for (int i = 0; i < 4; ++i)                               \
    _Pragma("unroll") for (int n = 0; n < 4; ++n)                             \
        acc[(MQ)*4 + i][n] = __builtin_amdgcn_mfma_f32_16x16x32_bf16(         \
            AF[i], BW[n], acc[(MQ)*4 + i][n], 0, 0, 0);                       \
  __builtin_amdgcn_s_setprio(0);

template <bool OUT_BF16>
__global__ __launch_bounds__(512, 2) void gemm_8p(const __bf16* __restrict__ A,
                                                  const __bf16* __restrict__ Wt,
                                                  const float* __restrict__ bias,
                                                  void* __restrict__ Cout,
                                                  int K, int Nreal, int ldc,
                                                  int gx) {
  __shared__ __bf16 As[2][16384];
  __shared__ __bf16 Bs[2][16384];
  const int tid = threadIdx.x;
  const int lane = tid & 63, wid = tid >> 6;
  const int wr = wid >> 2, wc = wid & 3;  // 2 x 4 waves

  // T1: XCD-chunked bijective swizzle (gridDim.x % 8 == 0)
  const int nwg = gridDim.x;
  const int orig = blockIdx.x;
  const int wg = ((orig & 7) * (nwg >> 3)) + (orig >> 3);
  const int tm = (wg / gx) * 256, tn = (wg % gx) * 256;

  f32x4 acc[8][4] = {};
  bf16x8 afc[4], afn[4], bwc[4];

  // staging decode: q -> (row, swizzled col), linear LDS dest slot q
  const int q0 = tid, q1 = tid + 512;
  const int row0 = ((q0 >> 3) << 1) | ((q0 >> 2) & 1);
  const int c0e = (((q0 & 3) - (q0 >> 3)) & 3) * 8;
  const int row1 = ((q1 >> 3) << 1) | ((q1 >> 2) & 1);
  const int c1e = (((q1 & 3) - (q1 >> 3)) & 3) * 8;
  const long aoffg0 = (long)(tm + row0) * K + c0e;
  const long aoffg1 = (long)(tm + row1) * K + c1e;
  const long boffg0 = (long)(tn + row0) * K + c0e;
  const long boffg1 = (long)(tn + row1) * K + c1e;

  // per-lane read offsets (elements within a 16KB k-half)
  const int l15 = lane & 15, cl = lane >> 4;
  int aoffl[8], boffl[4];
#pragma unroll
  for (int mf = 0; mf < 8; ++mf) {
    int row = wr * 128 + (mf >> 2) * 64 + (mf & 3) * 16 + l15;
    aoffl[mf] = (row >> 1) * 64 + (((row & 1) << 2) | ((cl + (row >> 1)) & 3)) * 8;
  }
#pragma unroll
  for (int nf = 0; nf < 4; ++nf) {
    int row = wc * 64 + nf * 16 + l15;
    boffl[nf] = (row >> 1) * 64 + (((row & 1) << 2) | ((cl + (row >> 1)) & 3)) * 8;
  }

  // prologue: stage K-tile 0 into buf 0; certify kh0; preload first operands
  STAGE_A(0, 0, 0);
  STAGE_B(0, 0, 0);
  STAGE_A(0, 1, 32);
  STAGE_B(0, 1, 32);
  vm4();
  bar();  // kh0(buf0) certified for all waves
  READ_A(afc, 0, 0, 0);
  READ_B(bwc, 0, 0);

  const int nt = K >> 6;
  for (int T = 0; T < nt - 1; ++T) {
    const int d = T & 1, e = d ^ 1;
    const int kc = (T + 1) << 6;
    // P0: MFMA(MQ0,kh0) ; prefetch afn (kh0 certified) ; stage A0(next)
    STAGE_A(e, 0, kc);
    READ_A(afn, 1, 0, d);
    MFMA_BLK(0, afc, bwc);
    // P1: MFMA(MQ1,kh0) ; certify kh1(d) ; reads for kh1 right after barrier
    STAGE_B(e, 0, kc);
    MFMA_BLK(1, afn, bwc);
    vm4();
    bar();  // kh1(d) certified
    READ_A(afc, 0, 1, d);
    READ_B(bwc, 1, d);
    // P2: MFMA(MQ0,kh1) ; prefetch afn ; stage A1(next)
    STAGE_A(e, 1, kc + 32);
    READ_A(afn, 1, 1, d);
    MFMA_BLK(0, afc, bwc);
    // P3: MFMA(MQ1,kh1) ; certify kh0(e) ; reads for next tile
    STAGE_B(e, 1, kc + 32);
    MFMA_BLK(1, afn, bwc);
    vm4();
    bar();  // kh0(e) certified
    READ_A(afc, 0, 0, e);
    READ_B(bwc, 0, e);
  }
  {  // tail tile, no stages
    const int d = (nt - 1) & 1;
    READ_A(afn, 1, 0, d);
    MFMA_BLK(0, afc, bwc);
    MFMA_BLK(1, afn, bwc);
    vm0();
    bar();  // kh1(d) certified
    READ_A(afc, 0, 1, d);
    READ_B(bwc, 1, d);
    READ_A(afn, 1, 1, d);
    MFMA_BLK(0, afc, bwc);
    MFMA_BLK(1, afn, bwc);
  }

  // epilogue: frag D row=(lane>>4)*4+r, col=lane&15
#pragma unroll
  for (int mf = 0; mf < 8; ++mf) {
    const int rg = tm + wr * 128 + (mf >> 2) * 64 + (mf & 3) * 16 + (lane >> 4) * 4;
#pragma unroll
    for (int nf = 0; nf < 4; ++nf) {
      int col = tn + wc * 64 + nf * 16 + l15;
      if (col < Nreal) {
        float bv = bias[col];
#pragma unroll
        for (int r = 0; r < 4; ++r) {
          long row = rg + r;
          float v = acc[mf][nf][r] + bv;
          if (OUT_BF16) ((__bf16*)Cout)[row * (long)ldc + col] = (__bf16)v;
          else          ((float*)Cout)[row * (long)ldc + col] = v;
        }
      }
    }
  }
}

// ---- u = y * sigmoid(in_gate), layout u[b][m][t] ----
__global__ __launch_bounds__(256) void u_kernel(const __bf16* __restrict__ pre,
                                                float* __restrict__ u) {
  int i = blockIdx.x * 8 + (threadIdx.x >> 5);
  int m = threadIdx.x & 31;
  const __bf16* pr = pre + (long)i * 2112;
  float y = (float)pr[m];
  float g = (float)pr[1056 + m];
  float sg = 1.f / (1.f + expf(-g));
  int b = i >> 11, t = i & 2047;
  u[(long)((b * 32) + m) * 2048 + t] = y * sg;
}

// ---- scan: interleaved bf16 (re,im) to ws + Re(s) f32 to d_out ----
__global__ __launch_bounds__(64) void scan_kernel(const float* __restrict__ u,
                                                  const float* __restrict__ a,
                                                  const float* __restrict__ bfr,
                                                  __bf16* __restrict__ s_bf,
                                                  float* __restrict__ s_re) {
  int blk = blockIdx.x;
  int b = blk >> 4, mp = blk & 15;
  int lane = threadIdx.x;
  int mh = lane >> 5, c = lane & 31;
  int m = mp * 2 + mh;
  const float* ub = u + (long)(b * 32 + m) * 2048;
  float decay = expf(-fabsf(a[m]));
  float gr = decay * cosf(bfr[c]);
  float gi = decay * sinf(bfr[c]);
  float sr = 0.f, si = 0.f;
  long base = (long)b * 2048 * 1024 + m * 32 + c;
  for (int t = 0; t < 2048; ++t) {
    float uv = ub[t];
    float nr = fmaf(gr, sr, fmaf(-gi, si, uv));
    float ni_ = fmaf(gr, si, gi * sr);
    sr = nr; si = ni_;
    long ci = base + (long)t * 1024;
    bf16x2 zv; zv[0] = (__bf16)sr; zv[1] = (__bf16)si;
    *reinterpret_cast<bf16x2*>(s_bf + 2 * ci) = zv;
    s_re[ci] = sr;
  }
}

// ---- layernorm + gated mix: vectorized, in place on f32 z rows ----
__global__ __launch_bounds__(256) void ln_gate_kernel(float* __restrict__ z,
                                                      const __bf16* __restrict__ pre) {
  __shared__ float rs[4], rss[4];
  long row = blockIdx.x;
  float* zp = z + row * 1024;
  int tid = threadIdx.x;
  float4 v = *reinterpret_cast<const float4*>(zp + tid * 4);
  float s = v.x + v.y + v.z + v.w;
  float ss = v.x * v.x + v.y * v.y + v.z * v.z + v.w * v.w;
#pragma unroll
  for (int o = 32; o > 0; o >>= 1) {
    s += __shfl_down(s, o, 64);
    ss += __shfl_down(ss, o, 64);
  }
  if ((tid & 63) == 0) { rs[tid >> 6] = s; rss[tid >> 6] = ss; }
  __syncthreads();
  s = rs[0] + rs[1] + rs[2] + rs[3];
  ss = rss[0] + rss[1] + rss[2] + rss[3];
  float mean = s * (1.f / 1024.f);
  float var = ss * (1.f / 1024.f) - mean * mean;
  float rstd = rsqrtf(var + 1e-5f);
  const __bf16* pr = pre + row * 2112;
  bf16x4 th = *reinterpret_cast<const bf16x4*>(pr + 32 + tid * 4);
  bf16x4 og = *reinterpret_cast<const bf16x4*>(pr + 1088 + tid * 4);
  float4 o; float g;
  g = 1.f / (1.f + expf(-(float)og[0])); o.x = (v.x - mean) * rstd * g + (float)th[0] * (1.f - g);
  g = 1.f / (1.f + expf(-(float)og[1])); o.y = (v.y - mean) * rstd * g + (float)th[1] * (1.f - g);
  g = 1.f / (1.f + expf(-(float)og[2])); o.z = (v.z - mean) * rstd * g + (float)th[2] * (1.f - g);
  g = 1.f / (1.f + expf(-(float)og[3])); o.w = (v.w - mean) * rstd * g + (float)th[3] * (1.f - g);
  *reinterpret_cast<float4*>(zp + tid * 4) = o;
}

extern "C" void kernel_launch(void* const* d_in, const int* in_sizes, int n_in,
                              void* d_out, int out_size, void* d_ws, size_t ws_size,
                              hipStream_t stream) {
  const float* x = (const float*)d_in[0];
  const float* pre_w = (const float*)d_in[1];
  const float* pre_b = (const float*)d_in[2];
  const float* mix_w = (const float*)d_in[3];
  const float* mix_b = (const float*)d_in[4];
  const float* a = (const float*)d_in[5];
  const float* bfr = (const float*)d_in[6];

  // ws: buf0 (x_bf -> s_bf) | wtbuf (preWT then mixWT, sequential) | pre | u
  char* ws = (char*)d_ws;
  __bf16* buf0  = (__bf16*)(ws + 0);           // 67,108,864 B
  __bf16* wtbuf = (__bf16*)(ws + 67108864);    //  4,718,592 B [2304][1024] max
  __bf16* pre   = (__bf16*)(ws + 71827456);    // 69,206,016 B [16384][2112]
  float*  u     = (float*)(ws + 141033472);    //  2,097,152 B
  const size_t WS_NEEDED = 143130624ull;       // < proven 147,062,784
  if (ws_size < WS_NEEDED) return;

  __bf16* x_bf = buf0;
  __bf16* s_bf = buf0;

  float* out0 = (float*)d_out;                 // f32 [16384][1024]
  float* s_re = out0 + 16777216;               // f32 Re(s)

  cvt_f32_bf16<<<16384, 256, 0, stream>>>(x, x_bf, 16777216);
  transpose_to_bf16<<<dim3(72, 32), 256, 0, stream>>>(pre_w, wtbuf, 1024, 2112, 2304);
  gemm_8p<true><<<576, 512, 0, stream>>>(x_bf, wtbuf, pre_b, pre, 1024, 2112, 2112, 9);
  u_kernel<<<2048, 256, 0, stream>>>(pre, u);
  transpose_to_bf16<<<dim3(32, 64), 256, 0, stream>>>(mix_w, wtbuf, 2048, 1024, 1024);
  scan_kernel<<<128, 64, 0, stream>>>(u, a, bfr, s_bf, s_re);  // overwrites x_bf
  gemm_8p<false><<<256, 512, 0, stream>>>(s_bf, wtbuf, mix_b, out0, 2048, 1024, 1024, 4);
  ln_gate_kernel<<<16384, 256, 0, stream>>>(out0, pre);
}